// Round 7
// baseline (2038.703 us; speedup 1.0000x reference)
//
#include <hip/hip_runtime.h>

#define Bsz 128
#define Tn  1024
#define Dn  256
#define Hn  256

typedef _Float16 f16;
typedef _Float16 f16x4 __attribute__((ext_vector_type(4)));
typedef _Float16 f16x8 __attribute__((ext_vector_type(8)));
typedef float f32x4 __attribute__((ext_vector_type(4)));

union U8  { unsigned long long u;    f16x4 v; };
union U16 { unsigned long long u[2]; f16x8 v; };

// Exact tanh: 1 - 2/(e^{2x}+1). err ~1e-6, saturates correctly.
__device__ __forceinline__ float tanh_fast(float x) {
    float e = __builtin_amdgcn_exp2f(x * 2.88539008177793f);
    return 1.0f - 2.0f * __builtin_amdgcn_rcpf(e + 1.0f);
}

// LDS-only barrier (lgkm drain) — keeps global loads in flight across steps.
__device__ __forceinline__ void wg_barrier() {
    asm volatile("s_waitcnt lgkmcnt(0)\n\ts_barrier" ::: "memory");
}
// Full barrier: drain vmem+lds then sync (orders global h1 stores before flag).
__device__ __forceinline__ void full_barrier() {
    asm volatile("s_waitcnt vmcnt(0) lgkmcnt(0)\n\ts_barrier" ::: "memory");
}

// preB blob: pre1 value for (t, j, b) at f16 index ((t*64 + (j>>2))*128 + b)*4 + (j&3)
__device__ __forceinline__ size_t preB_off(int t, int j0, int b) {
    return ((size_t)t * 64 + (j0 >> 2)) * 512 + (size_t)b * 4;
}

// ---------------------------------------------------------------------------
// K1: preB[t][j][b] = x[b][t][:] . Wxh0[j][:] + b0[j]    (f16 blob out)
// grid = Tn/4 WGs (4 t each), 256 thr (4 waves x 64 j). Also zeroes flags.
// ---------------------------------------------------------------------------
__global__ __launch_bounds__(256, 2) void k_xproj(
    const float* __restrict__ x, const float* __restrict__ W,
    const float* __restrict__ bias, f16* __restrict__ preB,
    unsigned int* __restrict__ flags)
{
    __shared__ __align__(16) f16 xt[128][264];
    const int tid = threadIdx.x;
    if (blockIdx.x == 0 && tid < 8) flags[tid] = 0u;  // visible at kernel end

    const int lane = tid & 63, l15 = lane & 15, quad = lane >> 4;
    const int wbase = (tid >> 6) * 64;

    f16x8 wf[4][8];
    float4 bi[4];
    #pragma unroll
    for (int jn = 0; jn < 4; jn++) {
        int j = wbase + jn * 16 + l15;
        #pragma unroll
        for (int kk = 0; kk < 8; kk++)
            #pragma unroll
            for (int e = 0; e < 8; e++)
                wf[jn][kk][e] = (f16)W[(size_t)j * Dn + kk * 32 + quad * 8 + e];
    }
    #pragma unroll
    for (int jn = 0; jn < 4; jn++)
        bi[jn] = *(const float4*)(bias + wbase + jn * 16 + quad * 4);

    #pragma unroll 1
    for (int tt = 0; tt < 4; tt++) {
        const int t = blockIdx.x * 4 + tt;
        __syncthreads();  // WAR: previous GEMM reads of xt done
        for (int i = tid; i < 128 * 64; i += 256) {
            int row = i >> 6, c4 = i & 63;
            float4 v = *(const float4*)(x + ((size_t)row * Tn + t) * Dn + c4 * 4);
            f16x4 tv = { (f16)v.x, (f16)v.y, (f16)v.z, (f16)v.w };
            *(f16x4*)(&xt[row][c4 * 4]) = tv;
        }
        __syncthreads();

        #pragma unroll 1
        for (int bblk = 0; bblk < 8; bblk++) {
            f32x4 acc[4];
            #pragma unroll
            for (int jn = 0; jn < 4; jn++)
                acc[jn] = (f32x4){bi[jn].x, bi[jn].y, bi[jn].z, bi[jn].w};
            #pragma unroll
            for (int kk = 0; kk < 8; kk++) {
                f16x8 xb = *(const f16x8*)(&xt[bblk * 16 + l15][kk * 32 + quad * 8]);
                #pragma unroll
                for (int jn = 0; jn < 4; jn++)
                    acc[jn] = __builtin_amdgcn_mfma_f32_16x16x32_f16(wf[jn][kk], xb, acc[jn], 0, 0, 0);
            }
            #pragma unroll
            for (int jn = 0; jn < 4; jn++) {
                int j0 = wbase + jn * 16 + quad * 4;
                f16x4 pv = { (f16)acc[jn][0], (f16)acc[jn][1],
                             (f16)acc[jn][2], (f16)acc[jn][3] };
                *(f16x4*)(preB + preB_off(t, j0, bblk * 16 + l15)) = pv;
            }
        }
    }
}

// ---------------------------------------------------------------------------
// K2: pipelined recurrences. 16 WGs x 512 thr. stage = blockIdx>>3, tile = &7.
//  stage0 (WG 0-7):  h1[t] = tanh(pre1[t] + Whh0.h1[t-1]); publish h1g + flag
//  stage1 (WG 8-15): poll flag; h2[t] = tanh(b1 + Wxh1.h1[t] + Whh1.h2[t-1]);
//                    head on t=1023.
// h1g blob frag-major (== LDS layout): f16 idx kk*512 + lane*8 (+tile,t strides)
// ---------------------------------------------------------------------------
__global__ __launch_bounds__(512, 2) void k_rec(
    const float* __restrict__ Whh0, const float* __restrict__ Wxh1,
    const float* __restrict__ Whh1, const float* __restrict__ b1v,
    const float* __restrict__ fcw,  const float* __restrict__ fcb,
    const f16* __restrict__ preB,   f16* __restrict__ h1g,
    unsigned int* __restrict__ flags, float* __restrict__ out)
{
    __shared__ __align__(16) f16 h1f[2][4096];
    __shared__ __align__(16) f16 h2f[2][4096];

    const int tid  = threadIdx.x;
    const int lane = tid & 63, l15 = lane & 15, quad = lane >> 4;
    const int colbase = (tid >> 6) * 32;
    const int stage = blockIdx.x >> 3, tile = blockIdx.x & 7;
    const int bg = tile * 16;

    for (int i = tid; i < 4096; i += 512) {
        h1f[0][i] = (f16)0.0f; h1f[1][i] = (f16)0.0f;
        h2f[0][i] = (f16)0.0f; h2f[1][i] = (f16)0.0f;
    }

    int wroff[2];
    #pragma unroll
    for (int jn = 0; jn < 2; jn++) {
        int n0 = colbase + jn * 16 + quad * 4;
        wroff[jn] = (n0 >> 5) * 512 + ((n0 >> 3) & 3) * 128 + l15 * 8 + (n0 & 7);
    }

    if (stage == 0) {
        // ---- layer-1 recurrence ----
        f16x8 wh0[2][8];
        #pragma unroll
        for (int jn = 0; jn < 2; jn++) {
            int j = colbase + jn * 16 + l15;
            #pragma unroll
            for (int kk = 0; kk < 8; kk++)
                #pragma unroll
                for (int e = 0; e < 8; e++)
                    wh0[jn][kk][e] = (f16)Whh0[(size_t)j * Hn + kk * 32 + quad * 8 + e];
        }
        unsigned long long* gbase = (unsigned long long*)(h1g + (size_t)tile * Tn * 4096);
        unsigned int* flagp = flags + tile;

        f16x4 pnv[2];
        #pragma unroll
        for (int jn = 0; jn < 2; jn++)
            pnv[jn] = *(const f16x4*)(preB + preB_off(0, colbase + jn * 16 + quad * 4, bg + l15));
        __syncthreads();

#define S0STEP(P, TT) { \
    f32x4 accA[2]; \
    _Pragma("unroll") for (int jn = 0; jn < 2; jn++) \
        _Pragma("unroll") for (int r = 0; r < 4; r++) accA[jn][r] = (float)pnv[jn][r]; \
    { int tf = ((TT) + 1 < Tn) ? (TT) + 1 : Tn - 1; \
      _Pragma("unroll") for (int jn = 0; jn < 2; jn++) \
          pnv[jn] = *(const f16x4*)(preB + preB_off(tf, colbase + jn * 16 + quad * 4, bg + l15)); } \
    _Pragma("unroll") for (int kk = 0; kk < 8; kk++) { \
        f16x8 hb = *(const f16x8*)(&h1f[P][kk * 512 + lane * 8]); \
        accA[0] = __builtin_amdgcn_mfma_f32_16x16x32_f16(wh0[0][kk], hb, accA[0], 0, 0, 0); \
        accA[1] = __builtin_amdgcn_mfma_f32_16x16x32_f16(wh0[1][kk], hb, accA[1], 0, 0, 0); \
    } \
    unsigned long long* gp = gbase + (size_t)(TT) * 1024; \
    _Pragma("unroll") for (int jn = 0; jn < 2; jn++) { \
        f16x4 t4 = { (f16)tanh_fast(accA[jn][0]), (f16)tanh_fast(accA[jn][1]), \
                     (f16)tanh_fast(accA[jn][2]), (f16)tanh_fast(accA[jn][3]) }; \
        *(f16x4*)(&h1f[1-(P)][wroff[jn]]) = t4; \
        U8 uu; uu.v = t4; \
        __hip_atomic_store(gp + (wroff[jn] >> 2), uu.u, __ATOMIC_RELAXED, __HIP_MEMORY_SCOPE_AGENT); \
    } \
    full_barrier(); \
    if (tid == 0) \
        __hip_atomic_store(flagp, (unsigned)(TT) + 1u, __ATOMIC_RELAXED, __HIP_MEMORY_SCOPE_AGENT); \
}
        #pragma unroll 1
        for (int tp = 0; tp < Tn / 2; ++tp) {
            const int t0 = tp * 2;
            S0STEP(0, t0)
            S0STEP(1, (t0 + 1))
        }
#undef S0STEP
    } else {
        // ---- layer-2 recurrence + head ----
        f16x8 wx[2][8], wh1[2][8];
        #pragma unroll
        for (int jn = 0; jn < 2; jn++) {
            int j = colbase + jn * 16 + l15;
            #pragma unroll
            for (int kk = 0; kk < 8; kk++)
                #pragma unroll
                for (int e = 0; e < 8; e++) {
                    size_t o = (size_t)j * Hn + kk * 32 + quad * 8 + e;
                    wx [jn][kk][e] = (f16)Wxh1[o];
                    wh1[jn][kk][e] = (f16)Whh1[o];
                }
        }
        float4 bi[2];
        #pragma unroll
        for (int jn = 0; jn < 2; jn++)
            bi[jn] = *(const float4*)(b1v + colbase + jn * 16 + quad * 4);

        const unsigned long long* gbase =
            (const unsigned long long*)(h1g + (size_t)tile * Tn * 4096);
        unsigned int* flagp = flags + tile;
        unsigned int fl = 0u;
        __syncthreads();

#define S1STEP(Q, TT) { \
    unsigned int need = (unsigned)(TT) + 1u; \
    while (fl < need) \
        fl = __hip_atomic_load(flagp, __ATOMIC_RELAXED, __HIP_MEMORY_SCOPE_AGENT); \
    const unsigned long long* gp = gbase + (size_t)(TT) * 1024; \
    U16 hf[8]; \
    _Pragma("unroll") for (int kk = 0; kk < 8; kk++) { \
        hf[kk].u[0] = __hip_atomic_load(gp + kk * 128 + lane * 2,     __ATOMIC_RELAXED, __HIP_MEMORY_SCOPE_AGENT); \
        hf[kk].u[1] = __hip_atomic_load(gp + kk * 128 + lane * 2 + 1, __ATOMIC_RELAXED, __HIP_MEMORY_SCOPE_AGENT); \
    } \
    f32x4 accB[2]; \
    _Pragma("unroll") for (int jn = 0; jn < 2; jn++) \
        accB[jn] = (f32x4){bi[jn].x, bi[jn].y, bi[jn].z, bi[jn].w}; \
    _Pragma("unroll") for (int kk = 0; kk < 8; kk++) { \
        f16x8 h2b = *(const f16x8*)(&h2f[Q][kk * 512 + lane * 8]); \
        accB[0] = __builtin_amdgcn_mfma_f32_16x16x32_f16(wh1[0][kk], h2b, accB[0], 0, 0, 0); \
        accB[1] = __builtin_amdgcn_mfma_f32_16x16x32_f16(wh1[1][kk], h2b, accB[1], 0, 0, 0); \
    } \
    _Pragma("unroll") for (int kk = 0; kk < 8; kk++) { \
        accB[0] = __builtin_amdgcn_mfma_f32_16x16x32_f16(wx[0][kk], hf[kk].v, accB[0], 0, 0, 0); \
        accB[1] = __builtin_amdgcn_mfma_f32_16x16x32_f16(wx[1][kk], hf[kk].v, accB[1], 0, 0, 0); \
    } \
    fl = __hip_atomic_load(flagp, __ATOMIC_RELAXED, __HIP_MEMORY_SCOPE_AGENT); /* prefetch for t+1 */ \
    _Pragma("unroll") for (int jn = 0; jn < 2; jn++) { \
        f16x4 t4 = { (f16)tanh_fast(accB[jn][0]), (f16)tanh_fast(accB[jn][1]), \
                     (f16)tanh_fast(accB[jn][2]), (f16)tanh_fast(accB[jn][3]) }; \
        *(f16x4*)(&h2f[1-(Q)][wroff[jn]]) = t4; \
    } \
    wg_barrier(); \
}
        #pragma unroll 1
        for (int tp = 0; tp < Tn / 2; ++tp) {
            const int t0 = tp * 2;
            S1STEP(0, t0)
            S1STEP(1, (t0 + 1))
        }
#undef S1STEP

        // head: final h2 in h2f[0]
        if (tid < 256) {
            const int bl = tid >> 4, o = (tid >> 3) & 1, kc = tid & 7;
            float s = 0.f;
            #pragma unroll
            for (int kq = 0; kq < 32; kq++) {
                int k = kc * 32 + kq;
                f16 hv = h2f[0][(k >> 5) * 512 + ((k >> 3) & 3) * 128 + bl * 8 + (k & 7)];
                s += (float)hv * fcw[o * Hn + k];
            }
            s += __shfl_down(s, 4);
            s += __shfl_down(s, 2);
            s += __shfl_down(s, 1);
            if (kc == 0)
                out[(bg + bl) * 2 + o] = s + fcb[o];
        }
    }
}

extern "C" void kernel_launch(void* const* d_in, const int* in_sizes, int n_in,
                              void* d_out, int out_size, void* d_ws, size_t ws_size,
                              hipStream_t stream) {
    const float* x    = (const float*)d_in[0];
    const float* Wxh0 = (const float*)d_in[1];
    const float* Whh0 = (const float*)d_in[2];
    const float* b0   = (const float*)d_in[3];
    const float* Wxh1 = (const float*)d_in[4];
    const float* Whh1 = (const float*)d_in[5];
    const float* b1   = (const float*)d_in[6];
    const float* fcw  = (const float*)d_in[7];
    const float* fcb  = (const float*)d_in[8];
    float* out = (float*)d_out;

    f16* preB = (f16*)d_ws;                                    // 64 MiB
    f16* h1g  = (f16*)((char*)d_ws + ((size_t)64 << 20));      // 64 MiB
    unsigned int* flags = (unsigned int*)((char*)d_ws + ((size_t)128 << 20));  // 32 B

    k_xproj<<<dim3(Tn / 4), dim3(256), 0, stream>>>(x, Wxh0, b0, preB, flags);
    k_rec  <<<dim3(16),     dim3(512), 0, stream>>>(Whh0, Wxh1, Whh1, b1,
                                                    fcw, fcb, preB, h1g, flags, out);
}